// Round 7
// baseline (67.782 us; speedup 1.0000x reference)
//
#include <hip/hip_runtime.h>

// Patch gather: out[n, r, c] = images[(p0[n] + r) * W + p1[n] + c]
// Fixed geometry: H = W = 4096, width = 128, N = 4096.
//
// Band-decomposed schedule: work item = (patch x 64-row image band)
// intersection. All reads of an image band (1 MB) execute in one tight
// window, so each image line is fetched from HBM exactly once (~64 MB reads,
// the compulsory minimum) regardless of cache replacement; remaining traffic
// is the 268 MB compulsory nt-store stream.
//
//  1) order_kernel (1 block): for each patch, emit one int4 record
//     {n, p0, p1, band} per overlapped band (2-3 bands/patch), counting-
//     sorted by band into d_ws. Writes item count to d_ws[0].
//  2) band_gather_kernel: grid fixed at 3N (upper bound), chunked XCD
//     swizzle, early-exit on slot >= count. Each block copies its patch's
//     rows that fall inside its band (1..64 rows of 512 B).

#define IMG_W   4096
#define PATCH_W 128
#define BLOCK   256
#define BANDH   64
#define NBANDS  (4096 / BANDH)     // 64
#define MAX_ITEMS_PER_PATCH 3      // ceil((127 + BANDH) / BANDH)

typedef float f32x4 __attribute__((ext_vector_type(4)));

__global__ __launch_bounds__(1024) void order_kernel(
    const int* __restrict__ positions, int* __restrict__ cnt,
    int4* __restrict__ rec, int N)
{
    __shared__ int hist[NBANDS];
    __shared__ int cursor[NBANDS];
    const int tid = threadIdx.x;

    if (tid < NBANDS) hist[tid] = 0;
    __syncthreads();

    for (int i = tid; i < N; i += blockDim.x) {
        const int2 p = ((const int2*)positions)[i];
        const int b0 = p.x >> 6;
        const int b1 = (p.x + PATCH_W - 1) >> 6;
        for (int b = b0; b <= b1; ++b) atomicAdd(&hist[b], 1);
    }
    __syncthreads();

    if (tid == 0) {
        int s = 0;
        for (int b = 0; b < NBANDS; ++b) { cursor[b] = s; s += hist[b]; }
        *cnt = s;
    }
    __syncthreads();

    for (int i = tid; i < N; i += blockDim.x) {
        const int2 p = ((const int2*)positions)[i];
        const int b0 = p.x >> 6;
        const int b1 = (p.x + PATCH_W - 1) >> 6;
        for (int b = b0; b <= b1; ++b) {
            const int slot = atomicAdd(&cursor[b], 1);
            rec[slot] = make_int4(i, p.x, p.y, b);
        }
    }
}

__global__ __launch_bounds__(BLOCK) void band_gather_kernel(
    const float* __restrict__ images,
    const int*   __restrict__ cnt,
    const int4*  __restrict__ rec,
    float*       __restrict__ out,
    int grid_n)
{
    // chunked XCD swizzle over the fixed grid (grid_n divisible by 8)
    const int nper = grid_n >> 3;
    const int slot = (blockIdx.x & 7) * nper + (blockIdx.x >> 3);
    if (slot >= *cnt) return;

    const int4 r4 = rec[slot];
    const int n = r4.x, p0 = r4.y, p1 = r4.z, band = r4.w;

    const int r0    = max(p0, band * BANDH);              // first image row
    const int r1    = min(p0 + PATCH_W, band * BANDH + BANDH);
    const int nrows = r1 - r0;                            // 1..64

    const float* srcp = images + (size_t)r0 * IMG_W + p1;
    float*       dst  = out + (size_t)n * (PATCH_W * PATCH_W)
                            + (size_t)(r0 - p0) * PATCH_W;

    const int rowi = threadIdx.x >> 5;          // 0..7 (8 rows per iter)
    const int c    = (threadIdx.x & 31) << 2;   // float col within row

    #pragma unroll
    for (int it = 0; it < BANDH / 8; ++it) {
        const int r = it * 8 + rowi;
        if (r < nrows) {
            const float* s = srcp + (size_t)r * IMG_W + c;
            f32x4 v;
            v.x = s[0];
            v.y = s[1];
            v.z = s[2];
            v.w = s[3];
            __builtin_nontemporal_store(
                v, reinterpret_cast<f32x4*>(dst + (size_t)r * PATCH_W + c));
        }
    }
}

// Fallback (tiny ws): one block per patch, identity order.
__global__ __launch_bounds__(BLOCK) void patch_gather_kernel(
    const float* __restrict__ images,
    const int*   __restrict__ positions,
    float*       __restrict__ out)
{
    const int n  = blockIdx.x;
    const int p0 = positions[2 * n];
    const int p1 = positions[2 * n + 1];

    const float* srcp = images + (size_t)p0 * IMG_W + p1;
    float*       dst  = out + (size_t)n * (PATCH_W * PATCH_W);

    #pragma unroll
    for (int it = 0; it < (PATCH_W * PATCH_W / 4) / BLOCK; ++it) {
        const int i = it * BLOCK + threadIdx.x;
        const int r = i >> 5;
        const int c = (i & 31) << 2;
        const float* s = srcp + (size_t)r * IMG_W + c;
        f32x4 v;
        v.x = s[0]; v.y = s[1]; v.z = s[2]; v.w = s[3];
        __builtin_nontemporal_store(
            v, reinterpret_cast<f32x4*>(dst + (size_t)r * PATCH_W + c));
    }
}

extern "C" void kernel_launch(void* const* d_in, const int* in_sizes, int n_in,
                              void* d_out, int out_size, void* d_ws, size_t ws_size,
                              hipStream_t stream) {
    const float* images    = (const float*)d_in[0];
    const int*   positions = (const int*)d_in[1];
    float* out = (float*)d_out;

    const int N      = in_sizes[1] / 2;              // 4096 patches
    const int grid_n = MAX_ITEMS_PER_PATCH * N;      // 12288 (divisible by 8)
    const size_t need = 16 + (size_t)grid_n * sizeof(int4);

    if (ws_size >= need) {
        int*  cnt = (int*)d_ws;
        int4* rec = (int4*)((char*)d_ws + 16);
        order_kernel<<<1, 1024, 0, stream>>>(positions, cnt, rec, N);
        band_gather_kernel<<<grid_n, BLOCK, 0, stream>>>(images, cnt, rec, out, grid_n);
    } else {
        patch_gather_kernel<<<N, BLOCK, 0, stream>>>(images, positions, out);
    }
}